// Round 1
// baseline (596.498 us; speedup 1.0000x reference)
//
#include <hip/hip_runtime.h>

// ManifoldHyperConnections, R5.
// gemv: T=4096 x K=16384 x 25 outputs (24 cols + sumsq), split-K=32.
// Theory for this round: R4 was LDS-return-BW bound (w broadcast = 6 x
// ds_read_b128 per k per wave; (T/RG)*K*6*12cyc = 61us at RG=128) plus
// 2-barrier/tile drains. R5: RG=256 (4 rows/lane, halves w cost/FLOP),
// x as b128 granules in XOR-swizzled LDS (conflict-free), 1 barrier/tile
// dbuf, no global atomics (per-chunk stores + epilogue reduce), no memset.
// Sinkhorn: bitwise fixed-point early exit (exact-output preserving).

#define TROWS 4096
#define KDIM  16384
#define NOUT  24
#define RG    256                  // rows per workgroup (4 per lane)
#define KC    32                   // split-K chunks
#define KPER  (KDIM / KC)          // 512 k per block
#define TILEK 32                   // k per LDS tile
#define NTILE (KPER / TILEK)       // 16 tiles

__device__ __forceinline__ float fast_rcp(float x)   { return __builtin_amdgcn_rcpf(x); }
__device__ __forceinline__ float fast_rsqrt(float x) { return __builtin_amdgcn_rsqf(x); }

__global__ __launch_bounds__(256) void gemv_part(const float* __restrict__ x,
                                                 const float* __restrict__ w,
                                                 float* __restrict__ hacc) {
    // x tile: 256 rows x 32 k as float4 granules, XOR-swizzled:
    //   xb[buf][row*8 + (g ^ (row&7))] holds x[row][4g..4g+3]
    // read (lane -> rows lane+64c, fixed granule): bank-quad = (u4^(lane&7))&7 -> conflict-free
    // write (lane -> row (q>>3), g=q&7):            bank-quad = ((l&7)^(l>>3))   -> conflict-free
    __shared__ float4 xb[2][RG * TILEK / 4];    // 2 x 2048 x 16B = 64 KB
    __shared__ float4 wb[2][TILEK * NOUT / 4];  // 2 x  192 x 16B =  6 KB

    const int bid  = blockIdx.x;
    const int rb   = bid & 15;         // row block 0..15
    const int kc   = bid >> 4;         // split-K chunk 0..31
    const int rg0  = rb * RG;
    const int k0   = kc * KPER;

    const int t    = threadIdx.x;
    const int wv   = t >> 6;           // wave 0..3 -> k slice (8 k each per tile)
    const int lane = t & 63;
    const int xorl = lane & 7;

    float acc[4][NOUT + 1];
#pragma unroll
    for (int c = 0; c < 4; ++c)
#pragma unroll
        for (int j = 0; j <= NOUT; ++j) acc[c][j] = 0.0f;

    const float* xg = x + (size_t)rg0 * KDIM + k0;

    float4 px[8];
    float4 pw;

    auto loadT = [&](int kt) {
#pragma unroll
        for (int s = 0; s < 8; ++s) {
            const int q = t + 256 * s;             // tile float4 index 0..2047
            px[s] = *(const float4*)(xg + (size_t)(q >> 3) * KDIM + kt + 4 * (q & 7));
        }
        if (t < 192) pw = *(const float4*)(w + (size_t)(k0 + kt) * NOUT + 4 * t);
    };
    auto writeT = [&](int pn) {
#pragma unroll
        for (int s = 0; s < 8; ++s) {
            const int q   = t + 256 * s;
            const int row = q >> 3;
            const int g   = q & 7;
            xb[pn][row * 8 + (g ^ (row & 7))] = px[s];
        }
        if (t < 192) wb[pn][t] = pw;
    };

    // prologue: stage tile 0
    loadT(0);
    writeT(0);
    __syncthreads();

    int p = 0;
#pragma unroll 1
    for (int tile = 0; tile < NTILE; ++tile) {
        const bool more = (tile + 1 < NTILE);
        if (more) loadT((tile + 1) * TILEK);   // in flight across the whole compute

        const float4* xp = xb[p];
        const float*  wp = (const float*)wb[p];
#pragma unroll
        for (int gg = 0; gg < 2; ++gg) {
            const int u4 = 2 * wv + gg;        // this wave's granule (4 k's)
            float4 xv[4];
#pragma unroll
            for (int c = 0; c < 4; ++c)
                xv[c] = xp[(lane + 64 * c) * 8 + (u4 ^ xorl)];
#pragma unroll
            for (int kk = 0; kk < 4; ++kk) {
                const float4* wr = (const float4*)(wp + (u4 * 4 + kk) * NOUT);
                float wf[NOUT];
                *(float4*)(wf +  0) = wr[0];
                *(float4*)(wf +  4) = wr[1];
                *(float4*)(wf +  8) = wr[2];
                *(float4*)(wf + 12) = wr[3];
                *(float4*)(wf + 16) = wr[4];
                *(float4*)(wf + 20) = wr[5];
                const float x0 = kk == 0 ? xv[0].x : kk == 1 ? xv[0].y : kk == 2 ? xv[0].z : xv[0].w;
                const float x1 = kk == 0 ? xv[1].x : kk == 1 ? xv[1].y : kk == 2 ? xv[1].z : xv[1].w;
                const float x2 = kk == 0 ? xv[2].x : kk == 1 ? xv[2].y : kk == 2 ? xv[2].z : xv[2].w;
                const float x3 = kk == 0 ? xv[3].x : kk == 1 ? xv[3].y : kk == 2 ? xv[3].z : xv[3].w;
                acc[0][NOUT] = fmaf(x0, x0, acc[0][NOUT]);
                acc[1][NOUT] = fmaf(x1, x1, acc[1][NOUT]);
                acc[2][NOUT] = fmaf(x2, x2, acc[2][NOUT]);
                acc[3][NOUT] = fmaf(x3, x3, acc[3][NOUT]);
#pragma unroll
                for (int j = 0; j < NOUT; ++j) {
                    acc[0][j] = fmaf(wf[j], x0, acc[0][j]);
                    acc[1][j] = fmaf(wf[j], x1, acc[1][j]);
                    acc[2][j] = fmaf(wf[j], x2, acc[2][j]);
                    acc[3][j] = fmaf(wf[j], x3, acc[3][j]);
                }
            }
        }

        if (more) writeT(p ^ 1);   // loads had the full compute phase to land
        __syncthreads();           // single barrier per tile
        p ^= 1;
    }

    // 4-wave block reduce in LDS, then plain coalesced stores (no global atomics).
    float* lacc = (float*)xb;      // need 25*256 = 6400 floats; 16384 available
#pragma unroll 1
    for (int i = t; i < 25 * RG; i += 256) lacc[i] = 0.0f;
    __syncthreads();
#pragma unroll
    for (int c = 0; c < 4; ++c) {
        const int row = lane + 64 * c;
#pragma unroll
        for (int j = 0; j <= NOUT; ++j)
            atomicAdd(&lacc[j * RG + row], acc[c][j]);
    }
    __syncthreads();
    // hacc layout: [kc][j][row]  (KC x 25 x 4096 = 13.1 MB of ws)
#pragma unroll 1
    for (int i = t; i < 25 * RG; i += 256) {
        const int j = i >> 8;
        const int r = i & 255;
        hacc[((size_t)kc * 25 + j) * TROWS + rg0 + r] = lacc[i];
    }
}

__global__ __launch_bounds__(64) void sinkhorn_epilogue(const float* __restrict__ hacc,
                                                        const float* __restrict__ bias,
                                                        const float* __restrict__ alpha,
                                                        float* __restrict__ out) {
    const int row = blockIdx.x * 64 + threadIdx.x;

    // reduce the 32 split-K chunks (coalesced: lane == row)
    float h[25];
#pragma unroll
    for (int j = 0; j < 25; ++j) h[j] = 0.0f;
#pragma unroll 1
    for (int c = 0; c < KC; ++c) {
        const float* hp = hacc + (size_t)c * 25 * TROWS + row;
#pragma unroll
        for (int j = 0; j < 25; ++j) h[j] += hp[(size_t)j * TROWS];
    }

    const float r_inv = fast_rsqrt(h[24] * (1.0f / (float)KDIM));
    const float a0 = alpha[0], a1 = alpha[1], a2 = alpha[2];

#pragma unroll
    for (int i = 0; i < 4; ++i) {
        const float zpre = fmaf(r_inv * a0, h[i], bias[i]);
        out[(size_t)row * 4 + i] = fast_rcp(1.0f + __expf(-zpre));
        const float zpo = fmaf(r_inv * a1, h[4 + i], bias[4 + i]);
        out[(size_t)16384 + (size_t)row * 4 + i] = 2.0f * fast_rcp(1.0f + __expf(-zpo));
    }

    float E[16];
#pragma unroll
    for (int q = 0; q < 16; ++q)
        E[q] = __expf(fmaf(r_inv * a2, h[8 + q], bias[8 + q]));

    float u0 = 1.0f, u1 = 1.0f, u2 = 1.0f, u3 = 1.0f;
    float v0 = 1.0f, v1 = 1.0f, v2 = 1.0f, v3 = 1.0f;
    float pu0 = 1.0f, pu1 = 1.0f, pu2 = 1.0f, pu3 = 1.0f;
    float pv0 = 1.0f, pv1 = 1.0f, pv2 = 1.0f, pv3 = 1.0f;

    // Bitwise fixed-point early exit: once (u,v) is exactly unchanged for a
    // full iteration, all remaining iterations are identity -> exact output.
    // If it never triggers (e.g. a 2-cycle) we run the full 400 as before.
#pragma unroll 1
    for (int it = 0; it < 400; ++it) {
        float s0 = fmaf(E[0],  v0, E[1]  * v1) + fmaf(E[2],  v2, E[3]  * v3);
        float s1 = fmaf(E[4],  v0, E[5]  * v1) + fmaf(E[6],  v2, E[7]  * v3);
        float s2 = fmaf(E[8],  v0, E[9]  * v1) + fmaf(E[10], v2, E[11] * v3);
        float s3 = fmaf(E[12], v0, E[13] * v1) + fmaf(E[14], v2, E[15] * v3);
        u0 = fast_rcp(s0 + 1e-12f);
        u1 = fast_rcp(s1 + 1e-12f);
        u2 = fast_rcp(s2 + 1e-12f);
        u3 = fast_rcp(s3 + 1e-12f);
        float t0 = fmaf(E[0], u0, E[4]  * u1) + fmaf(E[8],  u2, E[12] * u3);
        float t1 = fmaf(E[1], u0, E[5]  * u1) + fmaf(E[9],  u2, E[13] * u3);
        float t2 = fmaf(E[2], u0, E[6]  * u1) + fmaf(E[10], u2, E[14] * u3);
        float t3 = fmaf(E[3], u0, E[7]  * u1) + fmaf(E[11], u2, E[15] * u3);
        v0 = fast_rcp(t0 + 1e-12f);
        v1 = fast_rcp(t1 + 1e-12f);
        v2 = fast_rcp(t2 + 1e-12f);
        v3 = fast_rcp(t3 + 1e-12f);

        const int conv = (u0 == pu0) & (u1 == pu1) & (u2 == pu2) & (u3 == pu3)
                       & (v0 == pv0) & (v1 == pv1) & (v2 == pv2) & (v3 == pv3);
        pu0 = u0; pu1 = u1; pu2 = u2; pu3 = u3;
        pv0 = v0; pv1 = v1; pv2 = v2; pv3 = v3;
        if (__all(conv)) break;
    }

    const size_t ob = 32768 + (size_t)row * 16;
    out[ob + 0]  = u0 * E[0]  * v0;
    out[ob + 1]  = u0 * E[1]  * v1;
    out[ob + 2]  = u0 * E[2]  * v2;
    out[ob + 3]  = u0 * E[3]  * v3;
    out[ob + 4]  = u1 * E[4]  * v0;
    out[ob + 5]  = u1 * E[5]  * v1;
    out[ob + 6]  = u1 * E[6]  * v2;
    out[ob + 7]  = u1 * E[7]  * v3;
    out[ob + 8]  = u2 * E[8]  * v0;
    out[ob + 9]  = u2 * E[9]  * v1;
    out[ob + 10] = u2 * E[10] * v2;
    out[ob + 11] = u2 * E[11] * v3;
    out[ob + 12] = u3 * E[12] * v0;
    out[ob + 13] = u3 * E[13] * v1;
    out[ob + 14] = u3 * E[14] * v2;
    out[ob + 15] = u3 * E[15] * v3;
}

extern "C" void kernel_launch(void* const* d_in, const int* in_sizes, int n_in,
                              void* d_out, int out_size, void* d_ws, size_t ws_size,
                              hipStream_t stream) {
    const float* x     = (const float*)d_in[0];
    const float* w     = (const float*)d_in[1];
    const float* bias  = (const float*)d_in[2];
    const float* alpha = (const float*)d_in[3];
    float* out  = (float*)d_out;
    float* hacc = (float*)d_ws;   // KC * 25 * 4096 floats = 13.1 MB

    // no memset: every hacc element is written unconditionally by gemv_part
    gemv_part<<<dim3((TROWS / RG) * KC), dim3(256), 0, stream>>>(x, w, hacc);
    sinkhorn_epilogue<<<dim3(TROWS / 64), dim3(64), 0, stream>>>(hacc, bias, alpha, out);
}

// Round 2
// 525.011 us; speedup vs baseline: 1.1362x; 1.1362x over previous
//
#include <hip/hip_runtime.h>

// ManifoldHyperConnections, R6.
// Theory: R4/R5 gemv was LDS-return-BW + latency bound because the 24 w
// values per k (wave-UNIFORM address) were read through the LDS pipe as
// b128 broadcasts. R6 moves w to the SCALAR pipe: inline-asm
// s_load_dwordx4 into SGPRs (constant cache), no w LDS buffer at all.
// Waves split (k-half x j-half): 12 outputs/wave -> 48 w-SGPRs live,
// ~100 FMA per 12 scalar loads. x keeps the conflict-free XOR-swizzled
// float4 LDS layout, 32KB dbuf -> 4-5 blocks/CU, ~16 waves/CU.
// Partials: 64 chunks (kc x kh) x 25 slots, plain coalesced stores
// (no atomics, no memset); epilogue reduces 64 chunks + Sinkhorn with
// bitwise fixed-point early exit.

typedef float f4 __attribute__((ext_vector_type(4)));

#define TROWS 4096
#define KDIM  16384
#define NOUT  24
#define RG    128                  // rows per workgroup (2 per lane)
#define KC    32                   // split-K chunks
#define KPER  (KDIM / KC)          // 512 k per block
#define TILEK 32                   // k per LDS tile
#define NTILE (KPER / TILEK)       // 16 tiles
#define NSLOT 25

__device__ __forceinline__ float fast_rcp(float x)   { return __builtin_amdgcn_rcpf(x); }
__device__ __forceinline__ float fast_rsqrt(float x) { return __builtin_amdgcn_rsqf(x); }

__global__ __launch_bounds__(256, 4) void gemv_part(const float* __restrict__ x,
                                                    const float* __restrict__ w,
                                                    float* __restrict__ hacc) {
    // x tile: 128 rows x 32 k as float4 granules, XOR-swizzled:
    //   xb[buf][row*8 + (g ^ (row&7))] holds x[row][4g..4g+3]
    // write quads (t&7)^((t>>3)&7) and read quads g^(lane&7) are both
    // 8-lanes-per-quad with distinct addresses -> minimum phases, conflict-free.
    __shared__ f4 xb[2][RG * TILEK / 4];   // 2 x 1024 x 16B = 32 KB

    const int bid  = blockIdx.x;
    const int rb   = bid & 31;         // row block 0..31
    const int kc   = bid >> 5;         // split-K chunk 0..31
    const int rg0  = rb * RG;
    const int k0   = kc * KPER;

    const int t    = threadIdx.x;
    const int wv   = t >> 6;
    const int lane = t & 63;
    const int kh   = wv & 1;           // k half of tile (16 k)
    const int jh   = wv >> 1;          // j half (12 outputs)
    const int xorl = lane & 7;

    float acc0[12], acc1[12], ss0 = 0.0f, ss1 = 0.0f;
#pragma unroll
    for (int j = 0; j < 12; ++j) { acc0[j] = 0.0f; acc1[j] = 0.0f; }

    const float* xg = x + (size_t)rg0 * KDIM + k0;

    f4 px[4];
    auto loadT = [&](int kt) {
#pragma unroll
        for (int s = 0; s < 4; ++s) {
            const int q   = t + 256 * s;           // granule 0..1023
            const int row = q >> 3;
            const int g   = q & 7;
            px[s] = *(const f4*)(xg + (size_t)row * KDIM + kt + 4 * g);
        }
    };
    auto writeT = [&](int pn) {
#pragma unroll
        for (int s = 0; s < 4; ++s) {
            const int q   = t + 256 * s;
            const int row = q >> 3;
            const int g   = q & 7;
            xb[pn][row * 8 + (g ^ (row & 7))] = px[s];
        }
    };

    loadT(0);
    writeT(0);
    __syncthreads();

    int p = 0;
#pragma unroll 1
    for (int tile = 0; tile < NTILE; ++tile) {
        const bool more = (tile + 1 < NTILE);
        if (more) loadT((tile + 1) * TILEK);   // in flight across compute

        // uniform scalar base for this wave's w block this tile:
        // rows k0 + tile*32 + kh*16 .., cols jh*12 ..
        const uint64_t wpv = (uint64_t)(w + ((size_t)(k0 + tile * TILEK + kh * 16)) * NOUT + jh * 12);
        const uint32_t plo = __builtin_amdgcn_readfirstlane((uint32_t)wpv);
        const uint32_t phi = __builtin_amdgcn_readfirstlane((uint32_t)(wpv >> 32));
        const uint64_t wps = ((uint64_t)phi << 32) | plo;

        const f4* xp = xb[p];
#pragma unroll
        for (int gi = 0; gi < 4; ++gi) {
            const int g = kh * 4 + gi;             // granule: k-local [4g,4g+3]
            f4 wa0, wa1, wa2, wb0, wb1, wb2, wc0, wc1, wc2, wd0, wd1, wd2;
            const uint64_t wq = wps + (uint64_t)gi * (4 * NOUT * 4); // 4 k rows * 96B
            asm volatile(
                "s_load_dwordx4 %[a0], %[p], 0x0\n\t"
                "s_load_dwordx4 %[a1], %[p], 0x10\n\t"
                "s_load_dwordx4 %[a2], %[p], 0x20\n\t"
                "s_load_dwordx4 %[b0], %[p], 0x60\n\t"
                "s_load_dwordx4 %[b1], %[p], 0x70\n\t"
                "s_load_dwordx4 %[b2], %[p], 0x80\n\t"
                "s_load_dwordx4 %[c0], %[p], 0xc0\n\t"
                "s_load_dwordx4 %[c1], %[p], 0xd0\n\t"
                "s_load_dwordx4 %[c2], %[p], 0xe0\n\t"
                "s_load_dwordx4 %[d0], %[p], 0x120\n\t"
                "s_load_dwordx4 %[d1], %[p], 0x130\n\t"
                "s_load_dwordx4 %[d2], %[p], 0x140\n\t"
                "s_waitcnt lgkmcnt(0)"
                : [a0]"=s"(wa0), [a1]"=s"(wa1), [a2]"=s"(wa2),
                  [b0]"=s"(wb0), [b1]"=s"(wb1), [b2]"=s"(wb2),
                  [c0]"=s"(wc0), [c1]"=s"(wc1), [c2]"=s"(wc2),
                  [d0]"=s"(wd0), [d1]"=s"(wd1), [d2]"=s"(wd2)
                : [p]"s"(wq));

            const f4 xv0 = xp[lane * 8 + (g ^ xorl)];
            const f4 xv1 = xp[(64 + lane) * 8 + (g ^ xorl)];

#define KSTEP(W0, W1, W2, KQ)                                              \
            {                                                              \
                const float a_ = xv0[KQ], b_ = xv1[KQ];                    \
                ss0 = fmaf(a_, a_, ss0);                                   \
                ss1 = fmaf(b_, b_, ss1);                                   \
                _Pragma("unroll")                                          \
                for (int m = 0; m < 4; ++m) {                              \
                    acc0[m]     = fmaf(W0[m], a_, acc0[m]);                \
                    acc1[m]     = fmaf(W0[m], b_, acc1[m]);                \
                    acc0[4 + m] = fmaf(W1[m], a_, acc0[4 + m]);            \
                    acc1[4 + m] = fmaf(W1[m], b_, acc1[4 + m]);            \
                    acc0[8 + m] = fmaf(W2[m], a_, acc0[8 + m]);            \
                    acc1[8 + m] = fmaf(W2[m], b_, acc1[8 + m]);            \
                }                                                          \
            }
            KSTEP(wa0, wa1, wa2, 0)
            KSTEP(wb0, wb1, wb2, 1)
            KSTEP(wc0, wc1, wc2, 2)
            KSTEP(wd0, wd1, wd2, 3)
#undef KSTEP
        }

        if (more) writeT(p ^ 1);   // px landed during compute (vmcnt wait here)
        __syncthreads();
        p ^= 1;
    }

    // plain coalesced stores; chunk = (kc, kh), 25 slots, no collisions:
    // jh=0 writes slots 0..11 and 24 (sumsq over its k-half); jh=1 writes 12..23.
    float* hb = hacc + ((size_t)(kc * 2 + kh) * NSLOT) * TROWS + rg0 + lane;
#pragma unroll
    for (int jj = 0; jj < 12; ++jj) {
        hb[(size_t)(jh * 12 + jj) * TROWS]      = acc0[jj];
        hb[(size_t)(jh * 12 + jj) * TROWS + 64] = acc1[jj];
    }
    if (jh == 0) {
        hb[(size_t)24 * TROWS]      = ss0;
        hb[(size_t)24 * TROWS + 64] = ss1;
    }
}

__global__ __launch_bounds__(64) void sinkhorn_epilogue(const float* __restrict__ hacc,
                                                        const float* __restrict__ bias,
                                                        const float* __restrict__ alpha,
                                                        float* __restrict__ out) {
    const int row = blockIdx.x * 64 + threadIdx.x;

    // reduce the 64 (kc x kh) chunks (coalesced: lane == row)
    float h[25];
#pragma unroll
    for (int j = 0; j < 25; ++j) h[j] = 0.0f;
#pragma unroll 1
    for (int c = 0; c < 2 * KC; ++c) {
        const float* hp = hacc + (size_t)c * NSLOT * TROWS + row;
#pragma unroll
        for (int j = 0; j < 25; ++j) h[j] += hp[(size_t)j * TROWS];
    }

    const float r_inv = fast_rsqrt(h[24] * (1.0f / (float)KDIM));
    const float a0 = alpha[0], a1 = alpha[1], a2 = alpha[2];

#pragma unroll
    for (int i = 0; i < 4; ++i) {
        const float zpre = fmaf(r_inv * a0, h[i], bias[i]);
        out[(size_t)row * 4 + i] = fast_rcp(1.0f + __expf(-zpre));
        const float zpo = fmaf(r_inv * a1, h[4 + i], bias[4 + i]);
        out[(size_t)16384 + (size_t)row * 4 + i] = 2.0f * fast_rcp(1.0f + __expf(-zpo));
    }

    float E[16];
#pragma unroll
    for (int q = 0; q < 16; ++q)
        E[q] = __expf(fmaf(r_inv * a2, h[8 + q], bias[8 + q]));

    float u0 = 1.0f, u1 = 1.0f, u2 = 1.0f, u3 = 1.0f;
    float v0 = 1.0f, v1 = 1.0f, v2 = 1.0f, v3 = 1.0f;
    float pu0 = 1.0f, pu1 = 1.0f, pu2 = 1.0f, pu3 = 1.0f;
    float pv0 = 1.0f, pv1 = 1.0f, pv2 = 1.0f, pv3 = 1.0f;

    // Bitwise fixed-point early exit: once (u,v) repeats exactly, all
    // remaining iterations are identity -> exact output. Falls back to
    // the full 400 if it never triggers.
#pragma unroll 1
    for (int it = 0; it < 400; ++it) {
        float s0 = fmaf(E[0],  v0, E[1]  * v1) + fmaf(E[2],  v2, E[3]  * v3);
        float s1 = fmaf(E[4],  v0, E[5]  * v1) + fmaf(E[6],  v2, E[7]  * v3);
        float s2 = fmaf(E[8],  v0, E[9]  * v1) + fmaf(E[10], v2, E[11] * v3);
        float s3 = fmaf(E[12], v0, E[13] * v1) + fmaf(E[14], v2, E[15] * v3);
        u0 = fast_rcp(s0 + 1e-12f);
        u1 = fast_rcp(s1 + 1e-12f);
        u2 = fast_rcp(s2 + 1e-12f);
        u3 = fast_rcp(s3 + 1e-12f);
        float t0 = fmaf(E[0], u0, E[4]  * u1) + fmaf(E[8],  u2, E[12] * u3);
        float t1 = fmaf(E[1], u0, E[5]  * u1) + fmaf(E[9],  u2, E[13] * u3);
        float t2 = fmaf(E[2], u0, E[6]  * u1) + fmaf(E[10], u2, E[14] * u3);
        float t3 = fmaf(E[3], u0, E[7]  * u1) + fmaf(E[11], u2, E[15] * u3);
        v0 = fast_rcp(t0 + 1e-12f);
        v1 = fast_rcp(t1 + 1e-12f);
        v2 = fast_rcp(t2 + 1e-12f);
        v3 = fast_rcp(t3 + 1e-12f);

        const int conv = (u0 == pu0) & (u1 == pu1) & (u2 == pu2) & (u3 == pu3)
                       & (v0 == pv0) & (v1 == pv1) & (v2 == pv2) & (v3 == pv3);
        pu0 = u0; pu1 = u1; pu2 = u2; pu3 = u3;
        pv0 = v0; pv1 = v1; pv2 = v2; pv3 = v3;
        if (__all(conv)) break;
    }

    const size_t ob = 32768 + (size_t)row * 16;
    out[ob + 0]  = u0 * E[0]  * v0;
    out[ob + 1]  = u0 * E[1]  * v1;
    out[ob + 2]  = u0 * E[2]  * v2;
    out[ob + 3]  = u0 * E[3]  * v3;
    out[ob + 4]  = u1 * E[4]  * v0;
    out[ob + 5]  = u1 * E[5]  * v1;
    out[ob + 6]  = u1 * E[6]  * v2;
    out[ob + 7]  = u1 * E[7]  * v3;
    out[ob + 8]  = u2 * E[8]  * v0;
    out[ob + 9]  = u2 * E[9]  * v1;
    out[ob + 10] = u2 * E[10] * v2;
    out[ob + 11] = u2 * E[11] * v3;
    out[ob + 12] = u3 * E[12] * v0;
    out[ob + 13] = u3 * E[13] * v1;
    out[ob + 14] = u3 * E[14] * v2;
    out[ob + 15] = u3 * E[15] * v3;
}

extern "C" void kernel_launch(void* const* d_in, const int* in_sizes, int n_in,
                              void* d_out, int out_size, void* d_ws, size_t ws_size,
                              hipStream_t stream) {
    const float* x     = (const float*)d_in[0];
    const float* w     = (const float*)d_in[1];
    const float* bias  = (const float*)d_in[2];
    const float* alpha = (const float*)d_in[3];
    float* out  = (float*)d_out;
    float* hacc = (float*)d_ws;   // 64 * 25 * 4096 floats = 26.2 MB

    // no memset: every hacc slot is written unconditionally by gemv_part
    gemv_part<<<dim3(32 * KC), dim3(256), 0, stream>>>(x, w, hacc);
    sinkhorn_epilogue<<<dim3(TROWS / 64), dim3(64), 0, stream>>>(hacc, bias, alpha, out);
}